// Round 17
// baseline (53.327 us; speedup 1.0000x reference)
//
#include <hip/hip_runtime.h>
#include <hip/hip_bf16.h>
#include <math.h>

#define BATCH 256
#define DM    768
#define REPR  1024
#define FF    3072

typedef __attribute__((ext_vector_type(8))) short bf16x8;
typedef __attribute__((ext_vector_type(4))) float f32x4;

__device__ __forceinline__ unsigned bf16rne(float f){
  union{float f; unsigned u;} x; x.f = f;
  return (x.u + 0x7FFFu + ((x.u >> 16) & 1u)) >> 16;
}
__device__ __forceinline__ unsigned pk2(float lo, float hi){
  return bf16rne(lo) | (bf16rne(hi) << 16);
}

// ---------------------------------------------------------------------------
// K1 gemm_g1 (r12-exact): G1 split-4: P1[z] = im @ Wv2 K-slices, B direct
// from raw f32 Wv2, depth-1 prefetch. Grid (12,8,4).
// ---------------------------------------------------------------------------
__global__ __launch_bounds__(256)
void gemm_g1(const float* __restrict__ Wv2, const float* __restrict__ im,
             float* __restrict__ P1)
{
  const int z = blockIdx.z, bx = blockIdx.x, by = blockIdx.y;
  const int tid = threadIdx.x;
  const int lane = tid & 63, wid = tid >> 6;
  const int wr = wid >> 1, wc = wid & 1;
  const int arow = by * 32 + wr * 16 + (lane & 15);
  const int colb = bx * 64 + wc * 32;
  const int kq8  = (lane >> 4) * 8;
  const int kb   = z * 256;              // 8 K-steps per slice

  const float* apf  = im + (size_t)arow * REPR + kb + kq8;
  const int c0 = colb + (lane & 15), c1 = c0 + 16;
  const float* wrow = Wv2 + (size_t)(kb + kq8) * DM;

  f32x4 acc0 = (f32x4)(0.0f), acc1 = (f32x4)(0.0f);
  float4 a0c = *(const float4*)apf, a1c = *(const float4*)(apf + 4);
  float b0c[8], b1c[8];
  #pragma unroll
  for (int j = 0; j < 8; ++j) {
    b0c[j] = wrow[(size_t)j * DM + c0];
    b1c[j] = wrow[(size_t)j * DM + c1];
  }

  for (int s = 0; s < 8; ++s) {
    float4 a0n, a1n; float b0n[8], b1n[8];
    const bool more = (s + 1) < 8;
    if (more) {                          // depth-1 prefetch
      const float* a2 = apf + (s + 1) * 32;
      a0n = *(const float4*)a2; a1n = *(const float4*)(a2 + 4);
      const float* w2r = wrow + (size_t)(s + 1) * 32 * DM;
      #pragma unroll
      for (int j = 0; j < 8; ++j) {
        b0n[j] = w2r[(size_t)j * DM + c0];
        b1n[j] = w2r[(size_t)j * DM + c1];
      }
    }
    union U { unsigned u[4]; bf16x8 v; } afr, bfr0, bfr1;
    afr.u[0] = pk2(a0c.x, a0c.y); afr.u[1] = pk2(a0c.z, a0c.w);
    afr.u[2] = pk2(a1c.x, a1c.y); afr.u[3] = pk2(a1c.z, a1c.w);
    #pragma unroll
    for (int j = 0; j < 4; ++j) {
      bfr0.u[j] = pk2(b0c[2*j], b0c[2*j+1]);
      bfr1.u[j] = pk2(b1c[2*j], b1c[2*j+1]);
    }
    acc0 = __builtin_amdgcn_mfma_f32_16x16x32_bf16(afr.v, bfr0.v, acc0, 0, 0, 0);
    acc1 = __builtin_amdgcn_mfma_f32_16x16x32_bf16(afr.v, bfr1.v, acc1, 0, 0, 0);
    if (more) {
      a0c = a0n; a1c = a1n;
      #pragma unroll
      for (int j = 0; j < 8; ++j) { b0c[j] = b0n[j]; b1c[j] = b1n[j]; }
    }
  }

  const int crow = by * 32 + wr * 16 + (lane >> 4) * 4;
  float* dst = P1 + (size_t)z * BATCH * DM;
  #pragma unroll
  for (int nf = 0; nf < 2; ++nf) {
    const int c = colb + nf * 16 + (lane & 15);
    const f32x4 a = nf ? acc1 : acc0;
    #pragma unroll
    for (int r = 0; r < 4; ++r)
      dst[(size_t)(crow + r) * DM + c] = a[r];
  }
}

// ---------------------------------------------------------------------------
// K2 gemm_g2f: G2 with fixup RECOMPUTED in an LDS prologue (no sync, no
// fences -- the one untried fusion mechanism). Each block stages its 32
// x-rows: sum 4 P1 slices + bv2 (fixup_x's exact order -> bit-identical),
// pk2 to bf16, store into a 48KB octet-XOR-swizzled LDS tile
// (phys_octet = o ^ (r&7): read-time 2-way bank aliasing = free).
// Hot loop = r12-exact except A comes from LDS. Epi: +b1, gelu -> bf16 tbf.
// ---------------------------------------------------------------------------
__global__ __launch_bounds__(256)
void gemm_g2f(const float* __restrict__ P1, const float* __restrict__ bv2,
              const float* __restrict__ W1, const float* __restrict__ b1,
              ushort* __restrict__ tbf)
{
  __shared__ uint4 xs[3072];             // x[32 rows][96 octets] bf16, swizzled

  int id = blockIdx.y * 48 + blockIdx.x;
  id = (id & 7) * 48 + (id >> 3);        // XCD swizzle (384 % 8 == 0)
  const int bx = id / 8, by = id % 8;
  const int tid = threadIdx.x;

  // ---- prologue: stage x rows [by*32,+32) ----
  const size_t SL = (size_t)BATCH * DM;
  #pragma unroll
  for (int i = 0; i < 12; ++i) {
    const int gidx = tid + i * 256;      // [0,3072)
    const int r = gidx / 96, o = gidx % 96;
    const size_t e = (size_t)(by * 32 + r) * DM + o * 8;
    float4 s0 = *(const float4*)(P1 + e);
    float4 s1 = *(const float4*)(P1 + e + 4);
    #pragma unroll
    for (int z = 1; z < 4; ++z) {
      float4 v0 = *(const float4*)(P1 + (size_t)z * SL + e);
      float4 v1 = *(const float4*)(P1 + (size_t)z * SL + e + 4);
      s0.x += v0.x; s0.y += v0.y; s0.z += v0.z; s0.w += v0.w;
      s1.x += v1.x; s1.y += v1.y; s1.z += v1.z; s1.w += v1.w;
    }
    float4 bb0 = *(const float4*)(bv2 + o * 8);
    float4 bb1 = *(const float4*)(bv2 + o * 8 + 4);
    s0.x += bb0.x; s0.y += bb0.y; s0.z += bb0.z; s0.w += bb0.w;
    s1.x += bb1.x; s1.y += bb1.y; s1.z += bb1.z; s1.w += bb1.w;
    uint4 wv = { pk2(s0.x, s0.y), pk2(s0.z, s0.w),
                 pk2(s1.x, s1.y), pk2(s1.z, s1.w) };
    xs[r * 96 + (o ^ (r & 7))] = wv;
  }
  __syncthreads();

  // ---- hot loop (r12-exact B path; A from LDS) ----
  const int lane = tid & 63, wid = tid >> 6;
  const int wr = wid >> 1, wc = wid & 1;
  const int rloc = wr * 16 + (lane & 15);
  const int colb = bx * 64 + wc * 32;
  const int c0 = colb + (lane & 15), c1 = c0 + 16;
  const int kq = (lane >> 4) * 8;
  const int xbase = rloc * 96, xm = rloc & 7, xq = lane >> 4;
  const float* wrow = W1 + (size_t)kq * FF;

  f32x4 acc0 = (f32x4)(0.0f), acc1 = (f32x4)(0.0f);
  union U { uint4 q; bf16x8 v; };
  U a_c;
  a_c.q = xs[xbase + (xq ^ xm)];
  float b0c[8], b1c[8];
  #pragma unroll
  for (int j = 0; j < 8; ++j) {
    b0c[j] = wrow[(size_t)j * FF + c0];
    b1c[j] = wrow[(size_t)j * FF + c1];
  }

  for (int t = 0; t < 24; ++t) {
    U a_n; float b0n[8], b1n[8];
    const bool more = (t + 1) < 24;
    if (more) {                          // issue next-step loads before MFMA
      a_n.q = xs[xbase + ((xq + 4 * (t + 1)) ^ xm)];
      const float* w2r = wrow + (size_t)(t + 1) * 32 * FF;
      #pragma unroll
      for (int j = 0; j < 8; ++j) {
        b0n[j] = w2r[(size_t)j * FF + c0];
        b1n[j] = w2r[(size_t)j * FF + c1];
      }
    }
    union V { unsigned u[4]; bf16x8 v; } bfr0, bfr1;
    #pragma unroll
    for (int j = 0; j < 4; ++j) {
      bfr0.u[j] = pk2(b0c[2*j], b0c[2*j+1]);
      bfr1.u[j] = pk2(b1c[2*j], b1c[2*j+1]);
    }
    acc0 = __builtin_amdgcn_mfma_f32_16x16x32_bf16(a_c.v, bfr0.v, acc0, 0, 0, 0);
    acc1 = __builtin_amdgcn_mfma_f32_16x16x32_bf16(a_c.v, bfr1.v, acc1, 0, 0, 0);
    if (more) {
      a_c = a_n;
      #pragma unroll
      for (int j = 0; j < 8; ++j) { b0c[j] = b0n[j]; b1c[j] = b1n[j]; }
    }
  }

  const int crow = by * 32 + wr * 16 + (lane >> 4) * 4;
  #pragma unroll
  for (int nf = 0; nf < 2; ++nf) {
    const int c = colb + nf * 16 + (lane & 15);
    const f32x4 a = nf ? acc1 : acc0;
    #pragma unroll
    for (int r = 0; r < 4; ++r) {
      float v = a[r] + b1[c];
      v = 0.5f * v * (1.0f + erff(v * 0.70710678118654752f));
      tbf[(size_t)(crow + r) * FF + c] = (ushort)bf16rne(v);
    }
  }
}

// ---------------------------------------------------------------------------
// K3 gemm_g3 (r12-exact): A = tbf bf16; B direct from f32 W2 [FF][DM].
// Split-8, grid (12,8,8), 12 K-steps, depth-1. Epi: f32 partial -> P3[z].
// ---------------------------------------------------------------------------
__global__ __launch_bounds__(256)
void gemm_g3(const ushort* __restrict__ tbf, const float* __restrict__ W2,
             float* __restrict__ P3)
{
  int id = blockIdx.y * 12 + blockIdx.x;
  id = (id & 7) * 12 + (id >> 3);        // XCD swizzle (96 % 8 == 0)
  const int bx = id / 8, by = id % 8;

  const int lane = threadIdx.x & 63, wid = threadIdx.x >> 6;
  const int wr = wid >> 1, wc = wid & 1;
  const int arow = by * 32 + wr * 16 + (lane & 15);
  const int colb = bx * 64 + wc * 32;
  const int kq = (lane >> 4) * 8;
  const int kb = blockIdx.z * 384;

  const ushort* ap = tbf + (size_t)arow * FF + kb + kq;
  const int c0 = colb + (lane & 15), c1 = c0 + 16;
  const float* wrow = W2 + (size_t)(kb + kq) * DM;

  f32x4 acc0 = (f32x4)(0.0f), acc1 = (f32x4)(0.0f);
  union U { uint4 q; bf16x8 v; };
  U a_c;
  a_c.q = *(const uint4*)ap;
  float b0c[8], b1c[8];
  #pragma unroll
  for (int j = 0; j < 8; ++j) {
    b0c[j] = wrow[(size_t)j * DM + c0];
    b1c[j] = wrow[(size_t)j * DM + c1];
  }

  for (int t = 0; t < 12; ++t) {
    U a_n; float b0n[8], b1n[8];
    const bool more = (t + 1) < 12;
    if (more) {                          // issue next-step loads before MFMA
      a_n.q = *(const uint4*)(ap + (t + 1) * 32);
      const float* w2r = wrow + (size_t)(t + 1) * 32 * DM;
      #pragma unroll
      for (int j = 0; j < 8; ++j) {
        b0n[j] = w2r[(size_t)j * DM + c0];
        b1n[j] = w2r[(size_t)j * DM + c1];
      }
    }
    union V { unsigned u[4]; bf16x8 v; } bfr0, bfr1;
    #pragma unroll
    for (int j = 0; j < 4; ++j) {
      bfr0.u[j] = pk2(b0c[2*j], b0c[2*j+1]);
      bfr1.u[j] = pk2(b1c[2*j], b1c[2*j+1]);
    }
    acc0 = __builtin_amdgcn_mfma_f32_16x16x32_bf16(a_c.v, bfr0.v, acc0, 0, 0, 0);
    acc1 = __builtin_amdgcn_mfma_f32_16x16x32_bf16(a_c.v, bfr1.v, acc1, 0, 0, 0);
    if (more) {
      a_c = a_n;
      #pragma unroll
      for (int j = 0; j < 8; ++j) { b0c[j] = b0n[j]; b1c[j] = b1n[j]; }
    }
  }

  const int crow = by * 32 + wr * 16 + (lane >> 4) * 4;
  float* dst = P3 + (size_t)blockIdx.z * BATCH * DM;
  #pragma unroll
  for (int nf = 0; nf < 2; ++nf) {
    const int c = colb + nf * 16 + (lane & 15);
    const f32x4 a = nf ? acc1 : acc0;
    #pragma unroll
    for (int r = 0; r < 4; ++r)
      dst[(size_t)(crow + r) * DM + c] = a[r];
  }
}

// ---------------------------------------------------------------------------
// K4 ln_final (r10-proven): x = ((P1_0+P1_1)+P1_2+P1_3)+bv2 inline (fixup
// order), then y = (x + b2) + P3_0..7, LayerNorm -> out. 1 block/row.
// ---------------------------------------------------------------------------
__global__ __launch_bounds__(256)
void ln_final(const float* __restrict__ P1, const float* __restrict__ bv2,
              const float* __restrict__ P3, const float* __restrict__ b2,
              const float* __restrict__ g, const float* __restrict__ be,
              float* __restrict__ out)
{
  const int row = blockIdx.x, tid = threadIdx.x;
  const int lane = tid & 63, wave = tid >> 6;

  float v[3];
  #pragma unroll
  for (int i = 0; i < 3; ++i) {
    const int c = tid + i * 256;
    float x = P1[(size_t)row * DM + c];
    #pragma unroll
    for (int z = 1; z < 4; ++z) x += P1[((size_t)z * BATCH + row) * DM + c];
    x += bv2[c];
    float s = x + b2[c];
    #pragma unroll
    for (int z = 0; z < 8; ++z) s += P3[((size_t)z * BATCH + row) * DM + c];
    v[i] = s;
  }

  __shared__ float red[4];
  float s = v[0] + v[1] + v[2];
  #pragma unroll
  for (int o = 32; o > 0; o >>= 1) s += __shfl_down(s, o);
  if (lane == 0) red[wave] = s;
  __syncthreads();
  const float mu = (red[0] + red[1] + red[2] + red[3]) * (1.0f / 768.0f);
  __syncthreads();
  const float d0 = v[0] - mu, d1 = v[1] - mu, d2 = v[2] - mu;
  float q = d0*d0 + d1*d1 + d2*d2;
  #pragma unroll
  for (int o = 32; o > 0; o >>= 1) q += __shfl_down(q, o);
  if (lane == 0) red[wave] = q;
  __syncthreads();
  const float var = (red[0] + red[1] + red[2] + red[3]) * (1.0f / 768.0f);
  const float inv = rsqrtf(var + 1e-12f);

  float* o = out + (size_t)row * DM;
  o[tid      ] = d0 * inv * g[tid      ] + be[tid      ];
  o[tid + 256] = d1 * inv * g[tid + 256] + be[tid + 256];
  o[tid + 512] = d2 * inv * g[tid + 512] + be[tid + 512];
}

// ---------------------------------------------------------------------------
// 4 kernels: G1 (split-4) -> G2(+fixup recomputed in LDS prologue) ->
// G3 (split-8) -> LN(+fixup inline). No cross-block sync anywhere.
// Bit-identical numerics to r12. ws ~10.5 MB.
// ---------------------------------------------------------------------------
extern "C" void kernel_launch(void* const* d_in, const int* in_sizes, int n_in,
                              void* d_out, int out_size, void* d_ws, size_t ws_size,
                              hipStream_t stream)
{
  const float* im  = (const float*)d_in[0];
  const float* Wv2 = (const float*)d_in[12];
  const float* bv2 = (const float*)d_in[13];
  const float* W1  = (const float*)d_in[14];
  const float* b1  = (const float*)d_in[15];
  const float* W2  = (const float*)d_in[16];
  const float* b2  = (const float*)d_in[17];
  const float* g   = (const float*)d_in[18];
  const float* be  = (const float*)d_in[19];
  float* out = (float*)d_out;

  char* w = (char*)d_ws;
  float*  P1  = (float*) (w);                // 4*256*768*4 = 3145728
  ushort* tbf = (ushort*)(w + 3145728);      // 256*3072*2  = 1572864
  float*  P3  = (float*) (w + 4718592);      // 8*256*768*4 = 6291456 -> 10.5MB

  // K1: P1[z] = im @ Wv2 slices (direct f32 B, split-4)
  gemm_g1<<<dim3(12, 8, 4), 256, 0, stream>>>(Wv2, im, P1);
  // K2: tbf = bf16(gelu((sum P1 + bv2) @ W1 + b1)), fixup staged in LDS
  gemm_g2f<<<dim3(48, 8, 1), 256, 0, stream>>>(P1, bv2, W1, b1, tbf);
  // K3: P3[z] = (t @ W2) K-slices (direct f32 B, split-8)
  gemm_g3<<<dim3(12, 8, 8), 256, 0, stream>>>(tbf, W2, P3);
  // K4: LN(sum P1 + bv2 + sum P3 + b2) -> out
  ln_final<<<BATCH, 256, 0, stream>>>(P1, bv2, P3, b2, g, be, out);
}

// Round 18
// 48.725 us; speedup vs baseline: 1.0944x; 1.0944x over previous
//
#include <hip/hip_runtime.h>
#include <hip/hip_bf16.h>
#include <math.h>

#define BATCH 256
#define DM    768
#define REPR  1024
#define FF    3072

typedef __attribute__((ext_vector_type(8))) short bf16x8;
typedef __attribute__((ext_vector_type(4))) float f32x4;

__device__ __forceinline__ unsigned bf16rne(float f){
  union{float f; unsigned u;} x; x.f = f;
  return (x.u + 0x7FFFu + ((x.u >> 16) & 1u)) >> 16;
}
__device__ __forceinline__ unsigned pk2(float lo, float hi){
  return bf16rne(lo) | (bf16rne(hi) << 16);
}

// ---------------------------------------------------------------------------
// K1 gemm_g1f: G1 with INTRA-BLOCK split-K (the one untried fusion mechanism:
// no fences, no atomics, no redundant reads -- K-reduction via LDS +
// __syncthreads inside one block). 96 blocks x 1024 thr (16 waves):
// wave = (wz, wq) = K-slice [wz*256,+256) x output quadrant (wr,wc).
// Each wave runs the r12-exact 8-step depth-1 loop (same kb, same math ->
// partials bit-identical to r12's P1 slices). Reduce in fixup order
// (((z0+z1)+z2)+z3)+bv2 -> xf/xbf bit-identical to r12's fixup_x output.
// ---------------------------------------------------------------------------
__global__ __launch_bounds__(1024)
void gemm_g1f(const float* __restrict__ Wv2, const float* __restrict__ im,
              const float* __restrict__ bv2,
              float* __restrict__ xf, ushort* __restrict__ xbf)
{
  __shared__ float red0[3][4][64][4];    // 12 KB: z-partials of acc0
  __shared__ float red1[3][4][64][4];    // 12 KB: z-partials of acc1

  const int bx = blockIdx.x, by = blockIdx.y;
  const int tid = threadIdx.x;
  const int lane = tid & 63, wid = tid >> 6;   // wid in [0,16)
  const int wz = wid >> 2, wq = wid & 3;       // K-slice, output quadrant
  const int wr = wq >> 1, wc = wq & 1;
  const int arow = by * 32 + wr * 16 + (lane & 15);
  const int colb = bx * 64 + wc * 32;
  const int kq8  = (lane >> 4) * 8;
  const int kb   = wz * 256;             // 8 K-steps per wave (r12 chain len)

  const float* apf  = im + (size_t)arow * REPR + kb + kq8;
  const int c0 = colb + (lane & 15), c1 = c0 + 16;
  const float* wrow = Wv2 + (size_t)(kb + kq8) * DM;

  f32x4 acc0 = (f32x4)(0.0f), acc1 = (f32x4)(0.0f);
  float4 a0c = *(const float4*)apf, a1c = *(const float4*)(apf + 4);
  float b0c[8], b1c[8];
  #pragma unroll
  for (int j = 0; j < 8; ++j) {
    b0c[j] = wrow[(size_t)j * DM + c0];
    b1c[j] = wrow[(size_t)j * DM + c1];
  }

  for (int s = 0; s < 8; ++s) {
    float4 a0n, a1n; float b0n[8], b1n[8];
    const bool more = (s + 1) < 8;
    if (more) {                          // depth-1 prefetch (r12-exact)
      const float* a2 = apf + (s + 1) * 32;
      a0n = *(const float4*)a2; a1n = *(const float4*)(a2 + 4);
      const float* w2r = wrow + (size_t)(s + 1) * 32 * DM;
      #pragma unroll
      for (int j = 0; j < 8; ++j) {
        b0n[j] = w2r[(size_t)j * DM + c0];
        b1n[j] = w2r[(size_t)j * DM + c1];
      }
    }
    union U { unsigned u[4]; bf16x8 v; } afr, bfr0, bfr1;
    afr.u[0] = pk2(a0c.x, a0c.y); afr.u[1] = pk2(a0c.z, a0c.w);
    afr.u[2] = pk2(a1c.x, a1c.y); afr.u[3] = pk2(a1c.z, a1c.w);
    #pragma unroll
    for (int j = 0; j < 4; ++j) {
      bfr0.u[j] = pk2(b0c[2*j], b0c[2*j+1]);
      bfr1.u[j] = pk2(b1c[2*j], b1c[2*j+1]);
    }
    acc0 = __builtin_amdgcn_mfma_f32_16x16x32_bf16(afr.v, bfr0.v, acc0, 0, 0, 0);
    acc1 = __builtin_amdgcn_mfma_f32_16x16x32_bf16(afr.v, bfr1.v, acc1, 0, 0, 0);
    if (more) {
      a0c = a0n; a1c = a1n;
      #pragma unroll
      for (int j = 0; j < 8; ++j) { b0c[j] = b0n[j]; b1c[j] = b1n[j]; }
    }
  }

  // ---- intra-block K-reduction (LDS, __syncthreads only) ----
  if (wz != 0) {
    #pragma unroll
    for (int j = 0; j < 4; ++j) {
      red0[wz - 1][wq][lane][j] = acc0[j];
      red1[wz - 1][wq][lane][j] = acc1[j];
    }
  }
  __syncthreads();
  if (wz == 0) {
    // sum order: ((z0 + z1) + z2) + z3  (fixup_x's exact order)
    #pragma unroll
    for (int j = 0; j < 4; ++j) {
      float s0 = acc0[j], s1 = acc1[j];
      s0 += red0[0][wq][lane][j]; s1 += red1[0][wq][lane][j];
      s0 += red0[1][wq][lane][j]; s1 += red1[1][wq][lane][j];
      s0 += red0[2][wq][lane][j]; s1 += red1[2][wq][lane][j];
      acc0[j] = s0; acc1[j] = s1;
    }
    const int crow = by * 32 + wr * 16 + (lane >> 4) * 4;
    #pragma unroll
    for (int nf = 0; nf < 2; ++nf) {
      const int c = colb + nf * 16 + (lane & 15);
      const f32x4 a = nf ? acc1 : acc0;
      const float bb = bv2[c];
      #pragma unroll
      for (int r = 0; r < 4; ++r) {
        const float v = a[r] + bb;       // then + bv2 (fixup order)
        xf [(size_t)(crow + r) * DM + c] = v;
        xbf[(size_t)(crow + r) * DM + c] = (ushort)bf16rne(v);
      }
    }
  }
}

// ---------------------------------------------------------------------------
// K2 gemm_g2 (r12-exact): A = xbf bf16; B direct from f32 W1 [DM][FF].
// Grid (48,8), 24 K-steps, depth-1 prefetch. Epi: +b1, exact gelu -> bf16.
// ---------------------------------------------------------------------------
__global__ __launch_bounds__(256)
void gemm_g2(const ushort* __restrict__ xbf, const float* __restrict__ W1,
             const float* __restrict__ b1, ushort* __restrict__ tbf)
{
  int id = blockIdx.y * 48 + blockIdx.x;
  id = (id & 7) * 48 + (id >> 3);        // XCD swizzle (384 % 8 == 0)
  const int bx = id / 8, by = id % 8;

  const int lane = threadIdx.x & 63, wid = threadIdx.x >> 6;
  const int wr = wid >> 1, wc = wid & 1;
  const int arow = by * 32 + wr * 16 + (lane & 15);
  const int colb = bx * 64 + wc * 32;
  const int kq = (lane >> 4) * 8;

  const ushort* ap = xbf + (size_t)arow * DM + kq;
  const int c0 = colb + (lane & 15), c1 = c0 + 16;
  const float* wrow = W1 + (size_t)kq * FF;

  f32x4 acc0 = (f32x4)(0.0f), acc1 = (f32x4)(0.0f);
  union U { uint4 q; bf16x8 v; };
  U a_c;
  a_c.q = *(const uint4*)ap;
  float b0c[8], b1c[8];
  #pragma unroll
  for (int j = 0; j < 8; ++j) {
    b0c[j] = wrow[(size_t)j * FF + c0];
    b1c[j] = wrow[(size_t)j * FF + c1];
  }

  for (int t = 0; t < 24; ++t) {
    U a_n; float b0n[8], b1n[8];
    const bool more = (t + 1) < 24;
    if (more) {                          // issue next-step loads before MFMA
      a_n.q = *(const uint4*)(ap + (t + 1) * 32);
      const float* w2r = wrow + (size_t)(t + 1) * 32 * FF;
      #pragma unroll
      for (int j = 0; j < 8; ++j) {
        b0n[j] = w2r[(size_t)j * FF + c0];
        b1n[j] = w2r[(size_t)j * FF + c1];
      }
    }
    union V { unsigned u[4]; bf16x8 v; } bfr0, bfr1;
    #pragma unroll
    for (int j = 0; j < 4; ++j) {
      bfr0.u[j] = pk2(b0c[2*j], b0c[2*j+1]);
      bfr1.u[j] = pk2(b1c[2*j], b1c[2*j+1]);
    }
    acc0 = __builtin_amdgcn_mfma_f32_16x16x32_bf16(a_c.v, bfr0.v, acc0, 0, 0, 0);
    acc1 = __builtin_amdgcn_mfma_f32_16x16x32_bf16(a_c.v, bfr1.v, acc1, 0, 0, 0);
    if (more) {
      a_c = a_n;
      #pragma unroll
      for (int j = 0; j < 8; ++j) { b0c[j] = b0n[j]; b1c[j] = b1n[j]; }
    }
  }

  const int crow = by * 32 + wr * 16 + (lane >> 4) * 4;
  #pragma unroll
  for (int nf = 0; nf < 2; ++nf) {
    const int c = colb + nf * 16 + (lane & 15);
    const f32x4 a = nf ? acc1 : acc0;
    #pragma unroll
    for (int r = 0; r < 4; ++r) {
      float v = a[r] + b1[c];
      v = 0.5f * v * (1.0f + erff(v * 0.70710678118654752f));
      tbf[(size_t)(crow + r) * FF + c] = (ushort)bf16rne(v);
    }
  }
}

// ---------------------------------------------------------------------------
// K3 gemm_g3 (r12-exact): A = tbf bf16; B direct from f32 W2 [FF][DM].
// Split-8, grid (12,8,8), 12 K-steps, depth-1. Epi: f32 partial -> P3[z].
// ---------------------------------------------------------------------------
__global__ __launch_bounds__(256)
void gemm_g3(const ushort* __restrict__ tbf, const float* __restrict__ W2,
             float* __restrict__ P3)
{
  int id = blockIdx.y * 12 + blockIdx.x;
  id = (id & 7) * 12 + (id >> 3);        // XCD swizzle (96 % 8 == 0)
  const int bx = id / 8, by = id % 8;

  const int lane = threadIdx.x & 63, wid = threadIdx.x >> 6;
  const int wr = wid >> 1, wc = wid & 1;
  const int arow = by * 32 + wr * 16 + (lane & 15);
  const int colb = bx * 64 + wc * 32;
  const int kq = (lane >> 4) * 8;
  const int kb = blockIdx.z * 384;

  const ushort* ap = tbf + (size_t)arow * FF + kb + kq;
  const int c0 = colb + (lane & 15), c1 = c0 + 16;
  const float* wrow = W2 + (size_t)(kb + kq) * DM;

  f32x4 acc0 = (f32x4)(0.0f), acc1 = (f32x4)(0.0f);
  union U { uint4 q; bf16x8 v; };
  U a_c;
  a_c.q = *(const uint4*)ap;
  float b0c[8], b1c[8];
  #pragma unroll
  for (int j = 0; j < 8; ++j) {
    b0c[j] = wrow[(size_t)j * DM + c0];
    b1c[j] = wrow[(size_t)j * DM + c1];
  }

  for (int t = 0; t < 12; ++t) {
    U a_n; float b0n[8], b1n[8];
    const bool more = (t + 1) < 12;
    if (more) {                          // issue next-step loads before MFMA
      a_n.q = *(const uint4*)(ap + (t + 1) * 32);
      const float* w2r = wrow + (size_t)(t + 1) * 32 * DM;
      #pragma unroll
      for (int j = 0; j < 8; ++j) {
        b0n[j] = w2r[(size_t)j * DM + c0];
        b1n[j] = w2r[(size_t)j * DM + c1];
      }
    }
    union V { unsigned u[4]; bf16x8 v; } bfr0, bfr1;
    #pragma unroll
    for (int j = 0; j < 4; ++j) {
      bfr0.u[j] = pk2(b0c[2*j], b0c[2*j+1]);
      bfr1.u[j] = pk2(b1c[2*j], b1c[2*j+1]);
    }
    acc0 = __builtin_amdgcn_mfma_f32_16x16x32_bf16(a_c.v, bfr0.v, acc0, 0, 0, 0);
    acc1 = __builtin_amdgcn_mfma_f32_16x16x32_bf16(a_c.v, bfr1.v, acc1, 0, 0, 0);
    if (more) {
      a_c = a_n;
      #pragma unroll
      for (int j = 0; j < 8; ++j) { b0c[j] = b0n[j]; b1c[j] = b1n[j]; }
    }
  }

  const int crow = by * 32 + wr * 16 + (lane >> 4) * 4;
  float* dst = P3 + (size_t)blockIdx.z * BATCH * DM;
  #pragma unroll
  for (int nf = 0; nf < 2; ++nf) {
    const int c = colb + nf * 16 + (lane & 15);
    const f32x4 a = nf ? acc1 : acc0;
    #pragma unroll
    for (int r = 0; r < 4; ++r)
      dst[(size_t)(crow + r) * DM + c] = a[r];
  }
}

// ---------------------------------------------------------------------------
// K4 ln_final (r12-exact): y = xf + sum_{z<8} P3[z] + b2, LayerNorm -> out.
// ---------------------------------------------------------------------------
__global__ __launch_bounds__(256)
void ln_final(const float* __restrict__ P3, const float* __restrict__ xf,
              const float* __restrict__ b2, const float* __restrict__ g,
              const float* __restrict__ be, float* __restrict__ out)
{
  const int row = blockIdx.x, tid = threadIdx.x;
  const int lane = tid & 63, wave = tid >> 6;

  float v[3];
  #pragma unroll
  for (int i = 0; i < 3; ++i) {
    const int c = tid + i * 256;
    float s = xf[(size_t)row * DM + c] + b2[c];
    #pragma unroll
    for (int z = 0; z < 8; ++z) s += P3[((size_t)z * BATCH + row) * DM + c];
    v[i] = s;
  }

  __shared__ float red[4];
  float s = v[0] + v[1] + v[2];
  #pragma unroll
  for (int o = 32; o > 0; o >>= 1) s += __shfl_down(s, o);
  if (lane == 0) red[wave] = s;
  __syncthreads();
  const float mu = (red[0] + red[1] + red[2] + red[3]) * (1.0f / 768.0f);
  __syncthreads();
  const float d0 = v[0] - mu, d1 = v[1] - mu, d2 = v[2] - mu;
  float q = d0*d0 + d1*d1 + d2*d2;
  #pragma unroll
  for (int o = 32; o > 0; o >>= 1) q += __shfl_down(q, o);
  if (lane == 0) red[wave] = q;
  __syncthreads();
  const float var = (red[0] + red[1] + red[2] + red[3]) * (1.0f / 768.0f);
  const float inv = rsqrtf(var + 1e-12f);

  float* o = out + (size_t)row * DM;
  o[tid      ] = d0 * inv * g[tid      ] + be[tid      ];
  o[tid + 256] = d1 * inv * g[tid + 256] + be[tid + 256];
  o[tid + 512] = d2 * inv * g[tid + 512] + be[tid + 512];
}

// ---------------------------------------------------------------------------
// 4 kernels: G1(intra-block split-K, writes xf+xbf) -> G2 -> G3 (split-8)
// -> LN. No P1, no fixup, no cross-block sync. Bit-identical to r12.
// ws ~8.3 MB.
// ---------------------------------------------------------------------------
extern "C" void kernel_launch(void* const* d_in, const int* in_sizes, int n_in,
                              void* d_out, int out_size, void* d_ws, size_t ws_size,
                              hipStream_t stream)
{
  const float* im  = (const float*)d_in[0];
  const float* Wv2 = (const float*)d_in[12];
  const float* bv2 = (const float*)d_in[13];
  const float* W1  = (const float*)d_in[14];
  const float* b1  = (const float*)d_in[15];
  const float* W2  = (const float*)d_in[16];
  const float* b2  = (const float*)d_in[17];
  const float* g   = (const float*)d_in[18];
  const float* be  = (const float*)d_in[19];
  float* out = (float*)d_out;

  char* w = (char*)d_ws;
  ushort* xbf = (ushort*)(w);                // 256*768*2   = 393216
  ushort* tbf = (ushort*)(w + 393216);       // 256*3072*2  = 1572864
  float*  xf  = (float*) (w + 1966080);      // 256*768*4   = 786432
  float*  P3  = (float*) (w + 2752512);      // 8*256*768*4 = 6291456 -> 8.3MB

  // K1: x = im @ Wv2 + bv2 -> xf,xbf (intra-block split-K, 96x1024)
  gemm_g1f<<<dim3(12, 8), 1024, 0, stream>>>(Wv2, im, bv2, xf, xbf);
  // K2: tbf = bf16(gelu(x @ W1 + b1))   (direct f32 B)
  gemm_g2<<<dim3(48, 8, 1), 256, 0, stream>>>(xbf, W1, b1, tbf);
  // K3: P3[z] = (t @ W2) K-slices       (direct f32 B, split-8)
  gemm_g3<<<dim3(12, 8, 8), 256, 0, stream>>>(tbf, W2, P3);
  // K4: LN(xf + sum P3 + b2) -> out
  ln_final<<<BATCH, 256, 0, stream>>>(P3, xf, b2, g, be, out);
}

// Round 19
// 44.922 us; speedup vs baseline: 1.1871x; 1.0847x over previous
//
#include <hip/hip_runtime.h>
#include <hip/hip_bf16.h>
#include <math.h>

#define BATCH 256
#define DM    768
#define REPR  1024
#define FF    3072

typedef __attribute__((ext_vector_type(8))) short bf16x8;
typedef __attribute__((ext_vector_type(4))) float f32x4;

__device__ __forceinline__ unsigned bf16rne(float f){
  union{float f; unsigned u;} x; x.f = f;
  return (x.u + 0x7FFFu + ((x.u >> 16) & 1u)) >> 16;
}
__device__ __forceinline__ unsigned pk2(float lo, float hi){
  return bf16rne(lo) | (bf16rne(hi) << 16);
}

// ---------------------------------------------------------------------------
// FINAL (r12 verbatim, 44.9 us): 5 kernels, all GEMMs register-only MFMA with
// B read directly from row-major f32 weights (no transposes), depth-1
// prefetch, 32x64 tiles, XCD-swizzled grids, split-K where chains are long.
// Every alternative measured worse: fusion via grid-barrier/atomics/fence/
// hot-loop-expansion/prologue-recompute/intra-block-reduce (r6,r11,r14,r10,
// r17,r18), prefetch depth 2/8 (r13,r5), 32-wide tiles (r15), split-K x2
// (r16), weight pre-transpose (r8 vs r12).
// ---------------------------------------------------------------------------

// K1 gemm_g1: G1 split-4: P1[z] = im @ Wv2 K-slices. Grid (12,8,4).
__global__ __launch_bounds__(256)
void gemm_g1(const float* __restrict__ Wv2, const float* __restrict__ im,
             float* __restrict__ P1)
{
  const int z = blockIdx.z, bx = blockIdx.x, by = blockIdx.y;
  const int tid = threadIdx.x;
  const int lane = tid & 63, wid = tid >> 6;
  const int wr = wid >> 1, wc = wid & 1;
  const int arow = by * 32 + wr * 16 + (lane & 15);
  const int colb = bx * 64 + wc * 32;
  const int kq8  = (lane >> 4) * 8;
  const int kb   = z * 256;              // 8 K-steps per slice

  const float* apf  = im + (size_t)arow * REPR + kb + kq8;
  const int c0 = colb + (lane & 15), c1 = c0 + 16;
  const float* wrow = Wv2 + (size_t)(kb + kq8) * DM;

  f32x4 acc0 = (f32x4)(0.0f), acc1 = (f32x4)(0.0f);
  float4 a0c = *(const float4*)apf, a1c = *(const float4*)(apf + 4);
  float b0c[8], b1c[8];
  #pragma unroll
  for (int j = 0; j < 8; ++j) {
    b0c[j] = wrow[(size_t)j * DM + c0];
    b1c[j] = wrow[(size_t)j * DM + c1];
  }

  for (int s = 0; s < 8; ++s) {
    float4 a0n, a1n; float b0n[8], b1n[8];
    const bool more = (s + 1) < 8;
    if (more) {                          // depth-1 prefetch
      const float* a2 = apf + (s + 1) * 32;
      a0n = *(const float4*)a2; a1n = *(const float4*)(a2 + 4);
      const float* w2r = wrow + (size_t)(s + 1) * 32 * DM;
      #pragma unroll
      for (int j = 0; j < 8; ++j) {
        b0n[j] = w2r[(size_t)j * DM + c0];
        b1n[j] = w2r[(size_t)j * DM + c1];
      }
    }
    union U { unsigned u[4]; bf16x8 v; } afr, bfr0, bfr1;
    afr.u[0] = pk2(a0c.x, a0c.y); afr.u[1] = pk2(a0c.z, a0c.w);
    afr.u[2] = pk2(a1c.x, a1c.y); afr.u[3] = pk2(a1c.z, a1c.w);
    #pragma unroll
    for (int j = 0; j < 4; ++j) {
      bfr0.u[j] = pk2(b0c[2*j], b0c[2*j+1]);
      bfr1.u[j] = pk2(b1c[2*j], b1c[2*j+1]);
    }
    acc0 = __builtin_amdgcn_mfma_f32_16x16x32_bf16(afr.v, bfr0.v, acc0, 0, 0, 0);
    acc1 = __builtin_amdgcn_mfma_f32_16x16x32_bf16(afr.v, bfr1.v, acc1, 0, 0, 0);
    if (more) {
      a0c = a0n; a1c = a1n;
      #pragma unroll
      for (int j = 0; j < 8; ++j) { b0c[j] = b0n[j]; b1c[j] = b1n[j]; }
    }
  }

  const int crow = by * 32 + wr * 16 + (lane >> 4) * 4;
  float* dst = P1 + (size_t)z * BATCH * DM;
  #pragma unroll
  for (int nf = 0; nf < 2; ++nf) {
    const int c = colb + nf * 16 + (lane & 15);
    const f32x4 a = nf ? acc1 : acc0;
    #pragma unroll
    for (int r = 0; r < 4; ++r)
      dst[(size_t)(crow + r) * DM + c] = a[r];
  }
}

// K2 fixup_x: x = sum_z P1[z] + bv2 -> xf (f32) + xbf (bf16).
__global__ __launch_bounds__(256)
void fixup_x(const float* __restrict__ P1, const float* __restrict__ bv2,
             float* __restrict__ xf, ushort* __restrict__ xbf)
{
  const int e = (blockIdx.x * 256 + threadIdx.x) * 4;
  const int c = e % DM;
  float4 s = *(const float4*)(P1 + e);
  #pragma unroll
  for (int z = 1; z < 4; ++z) {
    float4 v = *(const float4*)(P1 + (size_t)z * BATCH * DM + e);
    s.x += v.x; s.y += v.y; s.z += v.z; s.w += v.w;
  }
  float4 bb = *(const float4*)(bv2 + c);
  s.x += bb.x; s.y += bb.y; s.z += bb.z; s.w += bb.w;
  *(float4*)(xf + e) = s;
  uint2 o = { pk2(s.x, s.y), pk2(s.z, s.w) };
  *(uint2*)(xbf + e) = o;
}

// K3 gemm_g2: A = xbf bf16; B direct from f32 W1 [DM][FF]. Grid (48,8).
__global__ __launch_bounds__(256)
void gemm_g2(const ushort* __restrict__ xbf, const float* __restrict__ W1,
             const float* __restrict__ b1, ushort* __restrict__ tbf)
{
  int id = blockIdx.y * 48 + blockIdx.x;
  id = (id & 7) * 48 + (id >> 3);        // XCD swizzle (384 % 8 == 0)
  const int bx = id / 8, by = id % 8;

  const int lane = threadIdx.x & 63, wid = threadIdx.x >> 6;
  const int wr = wid >> 1, wc = wid & 1;
  const int arow = by * 32 + wr * 16 + (lane & 15);
  const int colb = bx * 64 + wc * 32;
  const int kq = (lane >> 4) * 8;

  const ushort* ap = xbf + (size_t)arow * DM + kq;
  const int c0 = colb + (lane & 15), c1 = c0 + 16;
  const float* wrow = W1 + (size_t)kq * FF;

  f32x4 acc0 = (f32x4)(0.0f), acc1 = (f32x4)(0.0f);
  union U { uint4 q; bf16x8 v; };
  U a_c;
  a_c.q = *(const uint4*)ap;
  float b0c[8], b1c[8];
  #pragma unroll
  for (int j = 0; j < 8; ++j) {
    b0c[j] = wrow[(size_t)j * FF + c0];
    b1c[j] = wrow[(size_t)j * FF + c1];
  }

  for (int t = 0; t < 24; ++t) {
    U a_n; float b0n[8], b1n[8];
    const bool more = (t + 1) < 24;
    if (more) {                          // issue next-step loads before MFMA
      a_n.q = *(const uint4*)(ap + (t + 1) * 32);
      const float* w2r = wrow + (size_t)(t + 1) * 32 * FF;
      #pragma unroll
      for (int j = 0; j < 8; ++j) {
        b0n[j] = w2r[(size_t)j * FF + c0];
        b1n[j] = w2r[(size_t)j * FF + c1];
      }
    }
    union V { unsigned u[4]; bf16x8 v; } bfr0, bfr1;
    #pragma unroll
    for (int j = 0; j < 4; ++j) {
      bfr0.u[j] = pk2(b0c[2*j], b0c[2*j+1]);
      bfr1.u[j] = pk2(b1c[2*j], b1c[2*j+1]);
    }
    acc0 = __builtin_amdgcn_mfma_f32_16x16x32_bf16(a_c.v, bfr0.v, acc0, 0, 0, 0);
    acc1 = __builtin_amdgcn_mfma_f32_16x16x32_bf16(a_c.v, bfr1.v, acc1, 0, 0, 0);
    if (more) {
      a_c = a_n;
      #pragma unroll
      for (int j = 0; j < 8; ++j) { b0c[j] = b0n[j]; b1c[j] = b1n[j]; }
    }
  }

  const int crow = by * 32 + wr * 16 + (lane >> 4) * 4;
  #pragma unroll
  for (int nf = 0; nf < 2; ++nf) {
    const int c = colb + nf * 16 + (lane & 15);
    const f32x4 a = nf ? acc1 : acc0;
    #pragma unroll
    for (int r = 0; r < 4; ++r) {
      float v = a[r] + b1[c];
      v = 0.5f * v * (1.0f + erff(v * 0.70710678118654752f));
      tbf[(size_t)(crow + r) * FF + c] = (ushort)bf16rne(v);
    }
  }
}

// K4 gemm_g3: A = tbf bf16; B direct from f32 W2 [FF][DM]. Split-8 (12,8,8).
__global__ __launch_bounds__(256)
void gemm_g3(const ushort* __restrict__ tbf, const float* __restrict__ W2,
             float* __restrict__ P3)
{
  int id = blockIdx.y * 12 + blockIdx.x;
  id = (id & 7) * 12 + (id >> 3);        // XCD swizzle (96 % 8 == 0)
  const int bx = id / 8, by = id % 8;

  const int lane = threadIdx.x & 63, wid = threadIdx.x >> 6;
  const int wr = wid >> 1, wc = wid & 1;
  const int arow = by * 32 + wr * 16 + (lane & 15);
  const int colb = bx * 64 + wc * 32;
  const int kq = (lane >> 4) * 8;
  const int kb = blockIdx.z * 384;

  const ushort* ap = tbf + (size_t)arow * FF + kb + kq;
  const int c0 = colb + (lane & 15), c1 = c0 + 16;
  const float* wrow = W2 + (size_t)(kb + kq) * DM;

  f32x4 acc0 = (f32x4)(0.0f), acc1 = (f32x4)(0.0f);
  union U { uint4 q; bf16x8 v; };
  U a_c;
  a_c.q = *(const uint4*)ap;
  float b0c[8], b1c[8];
  #pragma unroll
  for (int j = 0; j < 8; ++j) {
    b0c[j] = wrow[(size_t)j * DM + c0];
    b1c[j] = wrow[(size_t)j * DM + c1];
  }

  for (int t = 0; t < 12; ++t) {
    U a_n; float b0n[8], b1n[8];
    const bool more = (t + 1) < 12;
    if (more) {                          // issue next-step loads before MFMA
      a_n.q = *(const uint4*)(ap + (t + 1) * 32);
      const float* w2r = wrow + (size_t)(t + 1) * 32 * DM;
      #pragma unroll
      for (int j = 0; j < 8; ++j) {
        b0n[j] = w2r[(size_t)j * DM + c0];
        b1n[j] = w2r[(size_t)j * DM + c1];
      }
    }
    union V { unsigned u[4]; bf16x8 v; } bfr0, bfr1;
    #pragma unroll
    for (int j = 0; j < 4; ++j) {
      bfr0.u[j] = pk2(b0c[2*j], b0c[2*j+1]);
      bfr1.u[j] = pk2(b1c[2*j], b1c[2*j+1]);
    }
    acc0 = __builtin_amdgcn_mfma_f32_16x16x32_bf16(a_c.v, bfr0.v, acc0, 0, 0, 0);
    acc1 = __builtin_amdgcn_mfma_f32_16x16x32_bf16(a_c.v, bfr1.v, acc1, 0, 0, 0);
    if (more) {
      a_c = a_n;
      #pragma unroll
      for (int j = 0; j < 8; ++j) { b0c[j] = b0n[j]; b1c[j] = b1n[j]; }
    }
  }

  const int crow = by * 32 + wr * 16 + (lane >> 4) * 4;
  float* dst = P3 + (size_t)blockIdx.z * BATCH * DM;
  #pragma unroll
  for (int nf = 0; nf < 2; ++nf) {
    const int c = colb + nf * 16 + (lane & 15);
    const f32x4 a = nf ? acc1 : acc0;
    #pragma unroll
    for (int r = 0; r < 4; ++r)
      dst[(size_t)(crow + r) * DM + c] = a[r];
  }
}

// K5 ln_final: y = xf + sum_{z<8} P3[z] + b2, LayerNorm -> out. 1 block/row.
__global__ __launch_bounds__(256)
void ln_final(const float* __restrict__ P3, const float* __restrict__ xf,
              const float* __restrict__ b2, const float* __restrict__ g,
              const float* __restrict__ be, float* __restrict__ out)
{
  const int row = blockIdx.x, tid = threadIdx.x;
  const int lane = tid & 63, wave = tid >> 6;

  float v[3];
  #pragma unroll
  for (int i = 0; i < 3; ++i) {
    const int c = tid + i * 256;
    float s = xf[(size_t)row * DM + c] + b2[c];
    #pragma unroll
    for (int z = 0; z < 8; ++z) s += P3[((size_t)z * BATCH + row) * DM + c];
    v[i] = s;
  }

  __shared__ float red[4];
  float s = v[0] + v[1] + v[2];
  #pragma unroll
  for (int o = 32; o > 0; o >>= 1) s += __shfl_down(s, o);
  if (lane == 0) red[wave] = s;
  __syncthreads();
  const float mu = (red[0] + red[1] + red[2] + red[3]) * (1.0f / 768.0f);
  __syncthreads();
  const float d0 = v[0] - mu, d1 = v[1] - mu, d2 = v[2] - mu;
  float q = d0*d0 + d1*d1 + d2*d2;
  #pragma unroll
  for (int o = 32; o > 0; o >>= 1) q += __shfl_down(q, o);
  if (lane == 0) red[wave] = q;
  __syncthreads();
  const float var = (red[0] + red[1] + red[2] + red[3]) * (1.0f / 768.0f);
  const float inv = rsqrtf(var + 1e-12f);

  float* o = out + (size_t)row * DM;
  o[tid      ] = d0 * inv * g[tid      ] + be[tid      ];
  o[tid + 256] = d1 * inv * g[tid + 256] + be[tid + 256];
  o[tid + 512] = d2 * inv * g[tid + 512] + be[tid + 512];
}

// 5 kernels: G1 (split-4) -> fixup -> G2 -> G3 (split-8) -> LN. ws ~11.2 MB.
extern "C" void kernel_launch(void* const* d_in, const int* in_sizes, int n_in,
                              void* d_out, int out_size, void* d_ws, size_t ws_size,
                              hipStream_t stream)
{
  const float* im  = (const float*)d_in[0];
  const float* Wv2 = (const float*)d_in[12];
  const float* bv2 = (const float*)d_in[13];
  const float* W1  = (const float*)d_in[14];
  const float* b1  = (const float*)d_in[15];
  const float* W2  = (const float*)d_in[16];
  const float* b2  = (const float*)d_in[17];
  const float* g   = (const float*)d_in[18];
  const float* be  = (const float*)d_in[19];
  float* out = (float*)d_out;

  char* w = (char*)d_ws;
  ushort* xbf = (ushort*)(w);                // 256*768*2   = 393216
  ushort* tbf = (ushort*)(w + 393216);       // 256*3072*2  = 1572864
  float*  xf  = (float*) (w + 1966080);      // 256*768*4   = 786432
  float*  P1  = (float*) (w + 2752512);      // 4*256*768*4 = 3145728
  float*  P3  = (float*) (w + 5898240);      // 8*256*768*4 = 6291456 -> 11.2MB

  // K1: P1[z] = im @ Wv2 slices (direct f32 B, split-4)
  gemm_g1<<<dim3(12, 8, 4), 256, 0, stream>>>(Wv2, im, P1);
  // K2: x = sum P1 + bv2 -> xf, xbf
  fixup_x<<<192, 256, 0, stream>>>(P1, bv2, xf, xbf);
  // K3: tbf = bf16(gelu(x @ W1 + b1))   (direct f32 B)
  gemm_g2<<<dim3(48, 8, 1), 256, 0, stream>>>(xbf, W1, b1, tbf);
  // K4: P3[z] = (t @ W2) K-slices       (direct f32 B, split-8)
  gemm_g3<<<dim3(12, 8, 8), 256, 0, stream>>>(tbf, W2, P3);
  // K5: LN(xf + sum P3 + b2) -> out
  ln_final<<<BATCH, 256, 0, stream>>>(P3, xf, b2, g, be, out);
}